// Round 12
// baseline (1675.945 us; speedup 1.0000x reference)
//
#include <hip/hip_runtime.h>

#define DD 1024

typedef int   i32x4  __attribute__((ext_vector_type(4)));
typedef int   i32x8  __attribute__((ext_vector_type(8)));
typedef float f32x4  __attribute__((ext_vector_type(4)));

__device__ __forceinline__ float sigm(float x) { return 1.0f / (1.0f + __expf(-x)); }
__device__ __forceinline__ float tanh_fast(float x) {
  float e = __expf(-2.0f * fabsf(x));
  float t = (1.0f - e) / (1.0f + e);
  return copysignf(t, x);
}
__device__ __forceinline__ unsigned pk_fp8x4(float a, float b, float c, float d) {
  int u = __builtin_amdgcn_cvt_pk_fp8_f32(a, b, 0, false);
  u = __builtin_amdgcn_cvt_pk_fp8_f32(c, d, u, true);
  return (unsigned)u;
}
__device__ __forceinline__ void keepv(i32x8& a, i32x8& b, i32x8& c, i32x8& d) {
  asm volatile("" : "+v"(a), "+v"(b), "+v"(c), "+v"(d));   // pin prefetch liveness
}

// Fragment image (16 KB per (128-row, 128-k) tile): addr(r, k) =
//   (k>>7)*16384 + (r>>3)*1024 + ((k>>4)&7)*128 + (r&7)*16 + (k&15)
// A image: rb-major (131072 B per rb). B image: db-major, n_t = (dgl>>4)*64+gate*16+(dgl&15).

// ---- one-time weight prep ----
__global__ __launch_bounds__(256) void prep_weights(
    const float* __restrict__ Wih, const float* __restrict__ Whh,
    const float* __restrict__ bih, const float* __restrict__ bhh,
    unsigned char* __restrict__ Wcat8, float* __restrict__ bias) {
  int i = blockIdx.x * 256 + threadIdx.x;
  int g = i >> 18;
  int rem = i & 262143;
  int n = rem >> 8;
  int k4 = rem & 255;
  const float4* wih4 = reinterpret_cast<const float4*>(Wih);
  const float4* whh4 = reinterpret_cast<const float4*>(Whh);
  float4 v;
  if (g == 0) {
    size_t idx = (size_t)n * 256 + k4;
    float4 a = wih4[idx], b = whh4[idx];
    v = make_float4(a.x + b.x, a.y + b.y, a.z + b.z, a.w + b.w);
  } else if (g == 1) {
    size_t idx = (size_t)(DD + n) * 256 + k4;
    float4 a = wih4[idx], b = whh4[idx];
    v = make_float4(a.x + b.x, a.y + b.y, a.z + b.z, a.w + b.w);
  } else if (g == 2) {
    size_t idx = (size_t)(2 * DD + n) * 256 + k4;
    v = wih4[idx];
  } else {
    size_t idx = (size_t)(2 * DD + n) * 256 + k4;
    v = whh4[idx];
  }
  unsigned pkd = pk_fp8x4(v.x * 32.0f, v.y * 32.0f, v.z * 32.0f, v.w * 32.0f);
  int db  = n >> 5;
  int dgl = n & 31;
  int n_t = (dgl >> 4) * 64 + g * 16 + (dgl & 15);
  int kt   = k4 >> 5;
  int gran = (k4 >> 2) & 7;
  int klo  = (k4 & 3) * 4;
  size_t addr = (size_t)db * 131072 + kt * 16384 + (n_t >> 3) * 1024 +
                gran * 128 + (n_t & 7) * 16 + klo;
  *reinterpret_cast<unsigned*>(Wcat8 + addr) = pkd;

  if (i < 4 * DD) {
    int bg = i >> 10, bn = i & 1023;
    float bv;
    if (bg == 0)      bv = bih[bn] + bhh[bn];
    else if (bg == 1) bv = bih[DD + bn] + bhh[DD + bn];
    else if (bg == 2) bv = bih[2 * DD + bn];
    else              bv = bhh[2 * DD + bn];
    bias[i] = bv;
  }
}

// ---- error GEMV + fp8 cast of state into tiled A image ----
__global__ __launch_bounds__(256) void error_cast(
    const float* S, const float* __restrict__ We, const float* __restrict__ be,
    unsigned char* __restrict__ Sb8, float* __restrict__ err) {
  __shared__ float part[4];
  const int row = blockIdx.x;
  const int t = threadIdx.x;
  float4 v = reinterpret_cast<const float4*>(S + (size_t)row * DD)[t];
  float4 w = reinterpret_cast<const float4*>(We)[t];
  float dot = v.x * w.x + v.y * w.y + v.z * w.z + v.w * w.w;
  int kt   = t >> 5;
  int gran = (t >> 2) & 7;
  int klo  = (t & 3) * 4;
  int r    = row & 127;
  size_t addr = (size_t)(row >> 7) * 131072 + kt * 16384 + (r >> 3) * 1024 +
                gran * 128 + (r & 7) * 16 + klo;
  *reinterpret_cast<unsigned*>(Sb8 + addr) = pk_fp8x4(v.x, v.y, v.z, v.w);
#pragma unroll
  for (int off = 32; off > 0; off >>= 1) dot += __shfl_xor(dot, off);
  if ((t & 63) == 0) part[t >> 6] = dot;
  __syncthreads();
  if (t == 0) err[row] = sigm(part[0] + part[1] + part[2] + part[3] + be[0]);
}

// ---- reduce per-row partial dots -> err = sigmoid(sum + be) ----
__global__ __launch_bounds__(256) void sigmoid_err(
    const float* __restrict__ errp, const float* __restrict__ be,
    float* __restrict__ err, int M) {
  int m = blockIdx.x * 256 + threadIdx.x;
  if (m >= M) return;
  const float4* p = reinterpret_cast<const float4*>(errp + (size_t)m * 64);
  float s = 0.f;
#pragma unroll
  for (int i = 0; i < 16; ++i) { float4 q = p[i]; s += q.x + q.y + q.z + q.w; }
  err[m] = sigm(s + be[0]);
}

// ---- fused 4-gate MX-fp8 GEMM + GRU epilogue, LDS-free, forced reg-dbuf ----
// Tile 128M x 128N(4g x 32dg), BK=128, 8 K-tiles, 4 waves (2M x 2N), wave 64x64.
// Named double-buffer + keep-alive asm pins next-tile loads live across the
// current 16-MFMA cluster (defeats compiler load-sinking; ~550cy flight/tile).
// FUSE: epilogue also writes iter-2 fp8 A-image (SbOut) + deterministic
// per-(m,db,wc) partial dots errp[m][64] (unique writer, no atomics).
template <bool FUSE>
__global__ __launch_bounds__(256, 2) void gru_fused_gemm(
    const unsigned char* __restrict__ Sb8,   // tiled A image (in)
    const unsigned char* __restrict__ Wcat8, // tiled B image
    const float* __restrict__ bias,          // [4096]
    const float* __restrict__ err,           // [M]
    const float* Sf,                         // [M][1024] f32 h (may alias out)
    float* out,
    const float* __restrict__ We,            // [1024] (FUSE)
    float* __restrict__ errp,                // [M][64] (FUSE)
    unsigned char* __restrict__ SbOut,       // tiled A image for next iter (FUSE)
    int M) {
  const int bid = blockIdx.x;
  const int x = bid & 7;
  const int c = bid >> 3;
  const int db = (x & 1) * 16 + (c & 15);
  const int rb = (x >> 1) * 64 + (c >> 4);

  const int tid = threadIdx.x;
  const int w = tid >> 6;
  const int lane = tid & 63;
  const int l15 = lane & 15;
  const int q = lane >> 4;
  const int wr = w >> 1, wc = w & 1;

  const int lanoff = (l15 >> 3) * 1024 + 2 * q * 128 + (l15 & 7) * 16;
  const unsigned char* Ab = Sb8 + (size_t)rb * 131072 + wr * 8192 + lanoff;
  const unsigned char* Bb = Wcat8 + (size_t)db * 131072 + wc * 8192 + lanoff;

  f32x4 acc[4][4];
#pragma unroll
  for (int mi = 0; mi < 4; ++mi)
#pragma unroll
    for (int g = 0; g < 4; ++g) acc[mi][g] = f32x4{0.f, 0.f, 0.f, 0.f};

  i32x8 aX[4], bX[4], aY[4], bY[4];

#define LOADSET(T, AARR, BARR)                                                 \
  {                                                                            \
    const unsigned char* Abt = Ab + (T) * 16384;                               \
    const unsigned char* Bbt = Bb + (T) * 16384;                               \
    _Pragma("unroll")                                                          \
    for (int mi = 0; mi < 4; ++mi) {                                           \
      i32x4 lo = *reinterpret_cast<const i32x4*>(Abt + mi * 2048);             \
      i32x4 hi = *reinterpret_cast<const i32x4*>(Abt + mi * 2048 + 128);       \
      AARR[mi] = __builtin_shufflevector(lo, hi, 0, 1, 2, 3, 4, 5, 6, 7);      \
    }                                                                          \
    _Pragma("unroll")                                                          \
    for (int g = 0; g < 4; ++g) {                                              \
      i32x4 lo = *reinterpret_cast<const i32x4*>(Bbt + g * 2048);              \
      i32x4 hi = *reinterpret_cast<const i32x4*>(Bbt + g * 2048 + 128);        \
      BARR[g] = __builtin_shufflevector(lo, hi, 0, 1, 2, 3, 4, 5, 6, 7);       \
    }                                                                          \
  }
#define MFMA16(AARR, BARR)                                                     \
  _Pragma("unroll")                                                            \
  for (int g = 0; g < 4; ++g)                                                  \
    _Pragma("unroll")                                                          \
    for (int mi = 0; mi < 4; ++mi)                                             \
      acc[mi][g] = __builtin_amdgcn_mfma_scale_f32_16x16x128_f8f6f4(           \
          AARR[mi], BARR[g], acc[mi][g], 0, 0, 0, 0x7F7F7F7F, 0, 0x7A7A7A7A);

  LOADSET(0, aX, bX)
#pragma unroll
  for (int tt = 0; tt < 4; ++tt) {
    LOADSET(2 * tt + 1, aY, bY)
    keepv(aY[0], aY[1], aY[2], aY[3]);
    keepv(bY[0], bY[1], bY[2], bY[3]);
    MFMA16(aX, bX)
    if (tt < 3) {
      LOADSET(2 * tt + 2, aX, bX)
      keepv(aX[0], aX[1], aX[2], aX[3]);
      keepv(bX[0], bX[1], bX[2], bX[3]);
    }
    MFMA16(aY, bY)
  }
#undef LOADSET
#undef MFMA16

  // ---- epilogue: r,z,n + out = h + e*(1-z)*(n-h)  [+ fused err/cast]
  const int dgcol = db * 32 + wc * 16 + l15;
  const float b_r = bias[dgcol];
  const float b_z = bias[DD + dgcol];
  const float b_i = bias[2 * DD + dgcol];
  const float b_h = bias[3 * DD + dgcol];
  float We_c = 0.f;
  if (FUSE) We_c = We[dgcol];
  // tiled A-image column constants for k = dgcol
  const size_t kpart = (size_t)(dgcol >> 7) * 16384 + ((dgcol >> 4) & 7) * 128 + (dgcol & 15);
#pragma unroll
  for (int mi = 0; mi < 4; ++mi) {
#pragma unroll
    for (int j = 0; j < 4; ++j) {
      int m = rb * 128 + wr * 64 + mi * 16 + q * 4 + j;
      float e = err[m];
      float hh = Sf[(size_t)m * DD + dgcol];
      float r = sigm(acc[mi][0][j] + b_r);
      float z = sigm(acc[mi][1][j] + b_z);
      float n = tanh_fast(acc[mi][2][j] + b_i + r * (acc[mi][3][j] + b_h));
      float o = hh + e * (1.0f - z) * (n - hh);
      out[(size_t)m * DD + dgcol] = o;
      if (FUSE) {
        int rr = m & 127;
        SbOut[(size_t)(m >> 7) * 131072 + kpart + (rr >> 3) * 1024 + (rr & 7) * 16] =
            (unsigned char)(__builtin_amdgcn_cvt_pk_fp8_f32(o, o, 0, false) & 0xFF);
        float v = o * We_c;
        v += __shfl_xor(v, 1);
        v += __shfl_xor(v, 2);
        v += __shfl_xor(v, 4);
        v += __shfl_xor(v, 8);
        if (l15 == 0) errp[(size_t)m * 64 + db * 2 + wc] = v;
      }
    }
  }
}

extern "C" void kernel_launch(void* const* d_in, const int* in_sizes, int n_in,
                              void* d_out, int out_size, void* d_ws, size_t ws_size,
                              hipStream_t stream) {
  const float* x   = (const float*)d_in[0];
  const float* Wih = (const float*)d_in[1];
  const float* Whh = (const float*)d_in[2];
  const float* bih = (const float*)d_in[3];
  const float* bhh = (const float*)d_in[4];
  const float* We  = (const float*)d_in[5];
  const float* be  = (const float*)d_in[6];
  float* out = (float*)d_out;
  const int M = in_sizes[0] / DD;   // 32768
  const int nwg = (M / 128) * 32;   // 8192

  char* ws = (char*)d_ws;
  const size_t SZ_IMG = (size_t)M * DD;          // 32 MB
  const size_t need_full = 2 * SZ_IMG + 4194304 + 16384 + (size_t)M * 64 * 4 + (size_t)M * 4;

  if (ws_size >= need_full) {
    unsigned char* SbA   = (unsigned char*)ws;
    unsigned char* SbB   = (unsigned char*)(ws + SZ_IMG);
    unsigned char* Wcat8 = (unsigned char*)(ws + 2 * SZ_IMG);
    float* bias = (float*)(ws + 2 * SZ_IMG + 4194304);
    float* errp = (float*)(ws + 2 * SZ_IMG + 4194304 + 16384);
    float* err  = (float*)(ws + 2 * SZ_IMG + 4194304 + 16384 + (size_t)M * 64 * 4);

    prep_weights<<<4096, 256, 0, stream>>>(Wih, Whh, bih, bhh, Wcat8, bias);
    error_cast<<<M, 256, 0, stream>>>(x, We, be, SbA, err);
    gru_fused_gemm<true><<<nwg, 256, 0, stream>>>(SbA, Wcat8, bias, err, x, out,
                                                  We, errp, SbB, M);
    sigmoid_err<<<(M + 255) / 256, 256, 0, stream>>>(errp, be, err, M);
    gru_fused_gemm<false><<<nwg, 256, 0, stream>>>(SbB, Wcat8, bias, err, out, out,
                                                   nullptr, nullptr, nullptr, M);
  } else {
    // fallback: R11 plain path (36.3 MB)
    unsigned char* SbA   = (unsigned char*)ws;
    unsigned char* Wcat8 = (unsigned char*)(ws + SZ_IMG);
    float* bias = (float*)(ws + SZ_IMG + 4194304);
    float* err  = (float*)(ws + SZ_IMG + 4194304 + 16384);

    prep_weights<<<4096, 256, 0, stream>>>(Wih, Whh, bih, bhh, Wcat8, bias);
    const float* S = x;
    for (int it = 0; it < 2; ++it) {
      error_cast<<<M, 256, 0, stream>>>(S, We, be, SbA, err);
      gru_fused_gemm<false><<<nwg, 256, 0, stream>>>(SbA, Wcat8, bias, err, S, out,
                                                     nullptr, nullptr, nullptr, M);
      S = out;
    }
  }
}

// Round 13
// 440.147 us; speedup vs baseline: 3.8077x; 3.8077x over previous
//
#include <hip/hip_runtime.h>

#define DD 1024

typedef int   i32x4  __attribute__((ext_vector_type(4)));
typedef int   i32x8  __attribute__((ext_vector_type(8)));
typedef float f32x16 __attribute__((ext_vector_type(16)));

__device__ __forceinline__ float sigm(float x) { return 1.0f / (1.0f + __expf(-x)); }
__device__ __forceinline__ float tanh_fast(float x) {
  float e = __expf(-2.0f * fabsf(x));
  float t = (1.0f - e) / (1.0f + e);
  return copysignf(t, x);
}
__device__ __forceinline__ void gload_lds16(const void* g, void* l) {
  __builtin_amdgcn_global_load_lds((const __attribute__((address_space(1))) void*)g,
                                   (__attribute__((address_space(3))) void*)l, 16, 0, 0);
}
__device__ __forceinline__ unsigned pk_fp8x4(float a, float b, float c, float d) {
  int u = __builtin_amdgcn_cvt_pk_fp8_f32(a, b, 0, false);
  u = __builtin_amdgcn_cvt_pk_fp8_f32(c, d, u, true);
  return (unsigned)u;
}

// Fragment image, BK=64: 8 KB per (128-row, 64-k) K-tile.
//   within-tile addr(r, kk) = (r>>3)*512 + (kk>>4)*128 + (r&7)*16 + (kk&15)
//   full addr = blk*131072 + kt*8192 + within   (kt = k>>6, kk = k&63)
// A image: blk = rb (row-block). B image: blk = db; B row n_t = gate*32 + dgl.
// Frag reads (32x32x64): lane quad = (r&7) -> 8 lanes/quad = 2/bank = free.
// Staging: image order == LDS order -> linear 1 KB per gload_lds16, lane-adjacent.

// ---- one-time weight prep: tiled B image + bias[4][1024] ----
// g=0: Wih_r+Whh_r ; g=1: Wih_z+Whh_z ; g=2: Wih_n ; g=3: Whh_n
__global__ __launch_bounds__(256) void prep_weights(
    const float* __restrict__ Wih, const float* __restrict__ Whh,
    const float* __restrict__ bih, const float* __restrict__ bhh,
    unsigned char* __restrict__ Wcat8, float* __restrict__ bias) {
  int i = blockIdx.x * 256 + threadIdx.x;   // 4-elem units over 4*D*D/4
  int g = i >> 18;
  int rem = i & 262143;
  int n = rem >> 8;
  int k4 = rem & 255;                       // k = 4*k4
  const float4* wih4 = reinterpret_cast<const float4*>(Wih);
  const float4* whh4 = reinterpret_cast<const float4*>(Whh);
  float4 v;
  if (g == 0) {
    size_t idx = (size_t)n * 256 + k4;
    float4 a = wih4[idx], b = whh4[idx];
    v = make_float4(a.x + b.x, a.y + b.y, a.z + b.z, a.w + b.w);
  } else if (g == 1) {
    size_t idx = (size_t)(DD + n) * 256 + k4;
    float4 a = wih4[idx], b = whh4[idx];
    v = make_float4(a.x + b.x, a.y + b.y, a.z + b.z, a.w + b.w);
  } else if (g == 2) {
    size_t idx = (size_t)(2 * DD + n) * 256 + k4;
    v = wih4[idx];
  } else {
    size_t idx = (size_t)(2 * DD + n) * 256 + k4;
    v = whh4[idx];
  }
  // scale x32 (exact) so weights leave e4m3 denormal zone; MX B-scale 2^-5 undoes it
  unsigned pkd = pk_fp8x4(v.x * 32.0f, v.y * 32.0f, v.z * 32.0f, v.w * 32.0f);

  int db  = n >> 5;
  int n_t = g * 32 + (n & 31);
  size_t addr = (size_t)db * 131072 + (size_t)(k4 >> 4) * 8192 +
                (n_t >> 3) * 512 + ((k4 >> 2) & 3) * 128 + (n_t & 7) * 16 +
                (k4 & 3) * 4;
  *reinterpret_cast<unsigned*>(Wcat8 + addr) = pkd;

  if (i < 4 * DD) {
    int bg = i >> 10, bn = i & 1023;
    float bv;
    if (bg == 0)      bv = bih[bn] + bhh[bn];
    else if (bg == 1) bv = bih[DD + bn] + bhh[DD + bn];
    else if (bg == 2) bv = bih[2 * DD + bn];
    else              bv = bhh[2 * DD + bn];
    bias[i] = bv;
  }
}

// ---- per-iteration: error GEMV + fp8 cast of state into tiled A image ----
__global__ __launch_bounds__(256) void error_cast(
    const float* S, const float* __restrict__ We, const float* __restrict__ be,
    unsigned char* __restrict__ Sb8, float* __restrict__ err) {
  __shared__ float part[4];
  const int row = blockIdx.x;
  const int t = threadIdx.x;                // k = 4t
  float4 v = reinterpret_cast<const float4*>(S + (size_t)row * DD)[t];
  float4 w = reinterpret_cast<const float4*>(We)[t];
  float dot = v.x * w.x + v.y * w.y + v.z * w.z + v.w * w.w;

  int r = row & 127;
  size_t addr = (size_t)(row >> 7) * 131072 + (size_t)(t >> 4) * 8192 +
                (r >> 3) * 512 + ((t >> 2) & 3) * 128 + (r & 7) * 16 +
                (t & 3) * 4;
  *reinterpret_cast<unsigned*>(Sb8 + addr) = pk_fp8x4(v.x, v.y, v.z, v.w);

#pragma unroll
  for (int off = 32; off > 0; off >>= 1) dot += __shfl_xor(dot, off);
  if ((t & 63) == 0) part[t >> 6] = dot;
  __syncthreads();
  if (t == 0) err[row] = sigm(part[0] + part[1] + part[2] + part[3] + be[0]);
}

// ---- fused 4-gate MX-fp8 GEMM + GRU epilogue (R7 structure + linear staging) ----
// Tile 128M x 128N(4g x 32dg), BK=64, 16 K-tiles, 4 waves; wave = 32M x 128N
// via 4x mfma_scale_f32_32x32x64_f8f6f4 (A scale 1.0=127, B scale 2^-5=122).
// LDS 32 KB (2 slots) -> 3+ blocks/CU. Staging = pure linear copy from the
// pre-swizzled images (4 x 1KB per wave per tile); vmcnt(4) counted gate,
// stage t+2 into the slot freed by lgkm(0)+barrier. Epilogue: all 4 gates
// lane-local (n_t = gate*32+dgl), no cross-lane exchange.
__global__ __launch_bounds__(256, 3) void gru_fused_gemm(
    const unsigned char* __restrict__ Sb8,   // tiled A image
    const unsigned char* __restrict__ Wcat8, // tiled B image
    const float* __restrict__ bias,          // [4096]
    const float* __restrict__ err,           // [M]
    const float* Sf,                         // [M][1024] f32 h (may alias out)
    float* out, int M) {
  __shared__ alignas(16) unsigned char As[2 * 8192];   // 16 KB
  __shared__ alignas(16) unsigned char Bs[2 * 8192];   // 16 KB

  // two-level XCD decode: xcd owns 16db x 64rb, db fast (proven FETCH win)
  const int bid = blockIdx.x;
  const int x = bid & 7;
  const int c = bid >> 3;
  const int db = (x & 1) * 16 + (c & 15);
  const int rb = (x >> 1) * 64 + (c >> 4);

  const int tid = threadIdx.x;
  const int w = tid >> 6;                  // 0..3 ; wave owns M rows w*32..+31
  const int lane = tid & 63;
  const int l31 = lane & 31;
  const int h = lane >> 5;

  // staging bases: wave w stages instrs j=w and j=w+4 (1 KB each) for A and B
  const unsigned char* sA0 = Sb8 + (size_t)rb * 131072 + (size_t)w * 1024 + lane * 16;
  const unsigned char* sB0 = Wcat8 + (size_t)db * 131072 + (size_t)w * 1024 + lane * 16;
  unsigned char* const dA0 = As + w * 1024;
  unsigned char* const dB0 = Bs + w * 1024;

  // frag read offsets (within 8 KB tile)
  const int ar = w * 32 + l31;
  const int aoff = (ar >> 3) * 512 + (2 * h) * 128 + (ar & 7) * 16;
  int boff[4];
#pragma unroll
  for (int g = 0; g < 4; ++g) {
    int br = g * 32 + l31;
    boff[g] = (br >> 3) * 512 + (2 * h) * 128 + (br & 7) * 16;
  }

  f32x16 acc[4];
#pragma unroll
  for (int g = 0; g < 4; ++g)
#pragma unroll
    for (int r = 0; r < 16; ++r) acc[g][r] = 0.0f;

  auto stage = [&](int t) {
    const int slot = (t & 1) * 8192;
    const size_t koff = (size_t)t * 8192;
    gload_lds16(sA0 + koff, dA0 + slot);
    gload_lds16(sA0 + koff + 4096, dA0 + slot + 4096);
    gload_lds16(sB0 + koff, dB0 + slot);
    gload_lds16(sB0 + koff + 4096, dB0 + slot + 4096);
  };

  stage(0);
  stage(1);

  for (int t = 0; t < 16; ++t) {
    const int sb = (t & 1) * 8192;
    if (t < 15) asm volatile("s_waitcnt vmcnt(4)" ::: "memory");
    else        asm volatile("s_waitcnt vmcnt(0)" ::: "memory");
    __builtin_amdgcn_s_barrier();

    const unsigned char* Ab = As + sb;
    const unsigned char* Bb = Bs + sb;
    i32x4 a0 = *reinterpret_cast<const i32x4*>(Ab + aoff);
    i32x4 a1 = *reinterpret_cast<const i32x4*>(Ab + aoff + 128);
    i32x8 a = __builtin_shufflevector(a0, a1, 0, 1, 2, 3, 4, 5, 6, 7);
    i32x8 bf[4];
#pragma unroll
    for (int g = 0; g < 4; ++g) {
      i32x4 b0 = *reinterpret_cast<const i32x4*>(Bb + boff[g]);
      i32x4 b1 = *reinterpret_cast<const i32x4*>(Bb + boff[g] + 128);
      bf[g] = __builtin_shufflevector(b0, b1, 0, 1, 2, 3, 4, 5, 6, 7);
    }
    asm volatile("s_waitcnt lgkmcnt(0)" ::: "memory");
    __builtin_amdgcn_s_barrier();               // slot sb free block-wide

    if (t <= 13) stage(t + 2);                  // into freed slot sb

    __builtin_amdgcn_s_setprio(1);
#pragma unroll
    for (int g = 0; g < 4; ++g)
      acc[g] = __builtin_amdgcn_mfma_scale_f32_32x32x64_f8f6f4(
          a, bf[g], acc[g], 0, 0, 0, 127, 0, 122);
    __builtin_amdgcn_s_setprio(0);
  }

  // ---- epilogue: r,z,n + out = h + e*(1-z)*(n-h)
  // C/D 32x32 layout: col = lane&31, row = (reg&3) + 8*(reg>>2) + 4*(lane>>5)
  const int dgcol = db * 32 + l31;
  const float b_r = bias[dgcol];
  const float b_z = bias[DD + dgcol];
  const float b_i = bias[2 * DD + dgcol];
  const float b_h = bias[3 * DD + dgcol];
#pragma unroll
  for (int reg = 0; reg < 16; ++reg) {
    int rowf = (reg & 3) + 8 * (reg >> 2) + 4 * h;
    int m = rb * 128 + w * 32 + rowf;
    float e = err[m];
    float hh = Sf[(size_t)m * DD + dgcol];
    float r = sigm(acc[0][reg] + b_r);
    float z = sigm(acc[1][reg] + b_z);
    float n = tanh_fast(acc[2][reg] + b_i + r * (acc[3][reg] + b_h));
    out[(size_t)m * DD + dgcol] = hh + e * (1.0f - z) * (n - hh);
  }
}

extern "C" void kernel_launch(void* const* d_in, const int* in_sizes, int n_in,
                              void* d_out, int out_size, void* d_ws, size_t ws_size,
                              hipStream_t stream) {
  const float* x   = (const float*)d_in[0];
  const float* Wih = (const float*)d_in[1];
  const float* Whh = (const float*)d_in[2];
  const float* bih = (const float*)d_in[3];
  const float* bhh = (const float*)d_in[4];
  const float* We  = (const float*)d_in[5];
  const float* be  = (const float*)d_in[6];
  float* out = (float*)d_out;
  const int M = in_sizes[0] / DD;   // 32768

  char* ws = (char*)d_ws;
  unsigned char* Sb8   = (unsigned char*)ws;                         // 32 MB (tiled)
  unsigned char* Wcat8 = (unsigned char*)(ws + (size_t)M * DD);      // 4 MB (tiled)
  float* bias = (float*)(ws + (size_t)M * DD + (size_t)4 * DD * DD);
  float* err  = (float*)(ws + (size_t)M * DD + (size_t)4 * DD * DD + (size_t)4 * DD * 4);

  prep_weights<<<4096, 256, 0, stream>>>(Wih, Whh, bih, bhh, Wcat8, bias);

  const int nwg = (M / 128) * 32;   // 8192
  const float* S = x;
  for (int it = 0; it < 2; ++it) {
    error_cast<<<M, 256, 0, stream>>>(S, We, be, Sb8, err);
    gru_fused_gemm<<<nwg, 256, 0, stream>>>(Sb8, Wcat8, bias, err, S, out, M);
    S = out;
  }
}

// Round 14
// 438.583 us; speedup vs baseline: 3.8213x; 1.0036x over previous
//
#include <hip/hip_runtime.h>

#define DD 1024

typedef int   i32x4  __attribute__((ext_vector_type(4)));
typedef int   i32x8  __attribute__((ext_vector_type(8)));
typedef float f32x16 __attribute__((ext_vector_type(16)));

__device__ __forceinline__ float sigm(float x) { return 1.0f / (1.0f + __expf(-x)); }
__device__ __forceinline__ float tanh_fast(float x) {
  float e = __expf(-2.0f * fabsf(x));
  float t = (1.0f - e) / (1.0f + e);
  return copysignf(t, x);
}
__device__ __forceinline__ void gload_lds16(const void* g, void* l) {
  __builtin_amdgcn_global_load_lds((const __attribute__((address_space(1))) void*)g,
                                   (__attribute__((address_space(3))) void*)l, 16, 0, 0);
}
__device__ __forceinline__ unsigned pk_fp8x4(float a, float b, float c, float d) {
  int u = __builtin_amdgcn_cvt_pk_fp8_f32(a, b, 0, false);
  u = __builtin_amdgcn_cvt_pk_fp8_f32(c, d, u, true);
  return (unsigned)u;
}

// Fragment image, BK=64: 8 KB per (128-row, 64-k) K-tile.
//   within-tile addr(r, kk) = (r>>3)*512 + (kk>>4)*128 + (r&7)*16 + (kk&15)
//   full addr = blk*131072 + kt*8192 + within   (kt = k>>6, kk = k&63)
// A image: blk = rb (row-block). B image: blk = db; B row n_t = gate*32 + dgl.
// Frag reads (32x32x64): lane quad = (r&7) -> 8 lanes/quad = 2/bank = free.
// Staging: image order == LDS order -> linear 1 KB per gload_lds16, lane-adjacent.

// ---- one-time weight prep: tiled B image + bias[4][1024] ----
// g=0: Wih_r+Whh_r ; g=1: Wih_z+Whh_z ; g=2: Wih_n ; g=3: Whh_n
__global__ __launch_bounds__(256) void prep_weights(
    const float* __restrict__ Wih, const float* __restrict__ Whh,
    const float* __restrict__ bih, const float* __restrict__ bhh,
    unsigned char* __restrict__ Wcat8, float* __restrict__ bias) {
  int i = blockIdx.x * 256 + threadIdx.x;   // 4-elem units over 4*D*D/4
  int g = i >> 18;
  int rem = i & 262143;
  int n = rem >> 8;
  int k4 = rem & 255;                       // k = 4*k4
  const float4* wih4 = reinterpret_cast<const float4*>(Wih);
  const float4* whh4 = reinterpret_cast<const float4*>(Whh);
  float4 v;
  if (g == 0) {
    size_t idx = (size_t)n * 256 + k4;
    float4 a = wih4[idx], b = whh4[idx];
    v = make_float4(a.x + b.x, a.y + b.y, a.z + b.z, a.w + b.w);
  } else if (g == 1) {
    size_t idx = (size_t)(DD + n) * 256 + k4;
    float4 a = wih4[idx], b = whh4[idx];
    v = make_float4(a.x + b.x, a.y + b.y, a.z + b.z, a.w + b.w);
  } else if (g == 2) {
    size_t idx = (size_t)(2 * DD + n) * 256 + k4;
    v = wih4[idx];
  } else {
    size_t idx = (size_t)(2 * DD + n) * 256 + k4;
    v = whh4[idx];
  }
  // scale x32 (exact) so weights leave e4m3 denormal zone; MX B-scale 2^-5 undoes it
  unsigned pkd = pk_fp8x4(v.x * 32.0f, v.y * 32.0f, v.z * 32.0f, v.w * 32.0f);

  int db  = n >> 5;
  int n_t = g * 32 + (n & 31);
  size_t addr = (size_t)db * 131072 + (size_t)(k4 >> 4) * 8192 +
                (n_t >> 3) * 512 + ((k4 >> 2) & 3) * 128 + (n_t & 7) * 16 +
                (k4 & 3) * 4;
  *reinterpret_cast<unsigned*>(Wcat8 + addr) = pkd;

  if (i < 4 * DD) {
    int bg = i >> 10, bn = i & 1023;
    float bv;
    if (bg == 0)      bv = bih[bn] + bhh[bn];
    else if (bg == 1) bv = bih[DD + bn] + bhh[DD + bn];
    else if (bg == 2) bv = bih[2 * DD + bn];
    else              bv = bhh[2 * DD + bn];
    bias[i] = bv;
  }
}

// ---- per-iteration: error GEMV + fp8 cast of state into tiled A image ----
__global__ __launch_bounds__(256) void error_cast(
    const float* S, const float* __restrict__ We, const float* __restrict__ be,
    unsigned char* __restrict__ Sb8, float* __restrict__ err) {
  __shared__ float part[4];
  const int row = blockIdx.x;
  const int t = threadIdx.x;                // k = 4t
  float4 v = reinterpret_cast<const float4*>(S + (size_t)row * DD)[t];
  float4 w = reinterpret_cast<const float4*>(We)[t];
  float dot = v.x * w.x + v.y * w.y + v.z * w.z + v.w * w.w;

  int r = row & 127;
  size_t addr = (size_t)(row >> 7) * 131072 + (size_t)(t >> 4) * 8192 +
                (r >> 3) * 512 + ((t >> 2) & 3) * 128 + (r & 7) * 16 +
                (t & 3) * 4;
  *reinterpret_cast<unsigned*>(Sb8 + addr) = pk_fp8x4(v.x, v.y, v.z, v.w);

#pragma unroll
  for (int off = 32; off > 0; off >>= 1) dot += __shfl_xor(dot, off);
  if ((t & 63) == 0) part[t >> 6] = dot;
  __syncthreads();
  if (t == 0) err[row] = sigm(part[0] + part[1] + part[2] + part[3] + be[0]);
}

// ---- fused 4-gate MX-fp8 GEMM + GRU epilogue ----
// Tile 128M x 128N(4g x 32dg), BK=64, 16 K-tiles, 4 waves; wave = 32M x 128N
// via 4x mfma_scale_f32_32x32x64_f8f6f4 (A scale 1.0=127, B scale 2^-5=122).
// LDS 32 KB (2 slots) -> 4 blocks/CU (launch_bounds(256,4); 128KB LDS/CU).
// Staging = pure linear copy from pre-swizzled images; vmcnt(4) counted gate,
// stage t+2 into the slot freed by lgkm(0)+barrier. K-loop FULLY UNROLLED so
// slot offsets fold into ds_read offset immediates (kills per-tile VALU).
__global__ __launch_bounds__(256, 4) void gru_fused_gemm(
    const unsigned char* __restrict__ Sb8,   // tiled A image
    const unsigned char* __restrict__ Wcat8, // tiled B image
    const float* __restrict__ bias,          // [4096]
    const float* __restrict__ err,           // [M]
    const float* Sf,                         // [M][1024] f32 h (may alias out)
    float* out, int M) {
  __shared__ alignas(16) unsigned char As[2 * 8192];   // 16 KB
  __shared__ alignas(16) unsigned char Bs[2 * 8192];   // 16 KB

  // two-level XCD decode: xcd owns 16db x 64rb, db fast (proven FETCH win)
  const int bid = blockIdx.x;
  const int x = bid & 7;
  const int c = bid >> 3;
  const int db = (x & 1) * 16 + (c & 15);
  const int rb = (x >> 1) * 64 + (c >> 4);

  const int tid = threadIdx.x;
  const int w = tid >> 6;                  // 0..3 ; wave owns M rows w*32..+31
  const int lane = tid & 63;
  const int l31 = lane & 31;
  const int h = lane >> 5;

  // staging bases: wave w stages instrs j=w and j=w+4 (1 KB each) for A and B
  const unsigned char* sA0 = Sb8 + (size_t)rb * 131072 + (size_t)w * 1024 + lane * 16;
  const unsigned char* sB0 = Wcat8 + (size_t)db * 131072 + (size_t)w * 1024 + lane * 16;
  unsigned char* const dA0 = As + w * 1024;
  unsigned char* const dB0 = Bs + w * 1024;

  // frag read offsets (within 8 KB tile)
  const int ar = w * 32 + l31;
  const int aoff = (ar >> 3) * 512 + (2 * h) * 128 + (ar & 7) * 16;
  int boff[4];
#pragma unroll
  for (int g = 0; g < 4; ++g) {
    int br = g * 32 + l31;
    boff[g] = (br >> 3) * 512 + (2 * h) * 128 + (br & 7) * 16;
  }

  f32x16 acc[4];
#pragma unroll
  for (int g = 0; g < 4; ++g)
#pragma unroll
    for (int r = 0; r < 16; ++r) acc[g][r] = 0.0f;

  auto stage = [&](int t) {
    const int slot = (t & 1) * 8192;
    const size_t koff = (size_t)t * 8192;
    gload_lds16(sA0 + koff, dA0 + slot);
    gload_lds16(sA0 + koff + 4096, dA0 + slot + 4096);
    gload_lds16(sB0 + koff, dB0 + slot);
    gload_lds16(sB0 + koff + 4096, dB0 + slot + 4096);
  };

  stage(0);
  stage(1);

#pragma unroll
  for (int t = 0; t < 16; ++t) {
    const int sb = (t & 1) * 8192;
    if (t < 15) asm volatile("s_waitcnt vmcnt(4)" ::: "memory");
    else        asm volatile("s_waitcnt vmcnt(0)" ::: "memory");
    __builtin_amdgcn_s_barrier();

    const unsigned char* Ab = As + sb;
    const unsigned char* Bb = Bs + sb;
    i32x4 a0 = *reinterpret_cast<const i32x4*>(Ab + aoff);
    i32x4 a1 = *reinterpret_cast<const i32x4*>(Ab + aoff + 128);
    i32x8 a = __builtin_shufflevector(a0, a1, 0, 1, 2, 3, 4, 5, 6, 7);
    i32x8 bf[4];
#pragma unroll
    for (int g = 0; g < 4; ++g) {
      i32x4 b0 = *reinterpret_cast<const i32x4*>(Bb + boff[g]);
      i32x4 b1 = *reinterpret_cast<const i32x4*>(Bb + boff[g] + 128);
      bf[g] = __builtin_shufflevector(b0, b1, 0, 1, 2, 3, 4, 5, 6, 7);
    }
    asm volatile("s_waitcnt lgkmcnt(0)" ::: "memory");
    __builtin_amdgcn_s_barrier();               // slot sb free block-wide

    if (t <= 13) stage(t + 2);                  // into freed slot sb

    __builtin_amdgcn_s_setprio(1);
#pragma unroll
    for (int g = 0; g < 4; ++g)
      acc[g] = __builtin_amdgcn_mfma_scale_f32_32x32x64_f8f6f4(
          a, bf[g], acc[g], 0, 0, 0, 127, 0, 122);
    __builtin_amdgcn_s_setprio(0);
  }

  // ---- epilogue: r,z,n + out = h + e*(1-z)*(n-h)
  // C/D 32x32 layout: col = lane&31, row = (reg&3) + 8*(reg>>2) + 4*(lane>>5)
  const int dgcol = db * 32 + l31;
  const float b_r = bias[dgcol];
  const float b_z = bias[DD + dgcol];
  const float b_i = bias[2 * DD + dgcol];
  const float b_h = bias[3 * DD + dgcol];
#pragma unroll
  for (int reg = 0; reg < 16; ++reg) {
    int rowf = (reg & 3) + 8 * (reg >> 2) + 4 * h;
    int m = rb * 128 + w * 32 + rowf;
    float e = err[m];
    float hh = Sf[(size_t)m * DD + dgcol];
    float r = sigm(acc[0][reg] + b_r);
    float z = sigm(acc[1][reg] + b_z);
    float n = tanh_fast(acc[2][reg] + b_i + r * (acc[3][reg] + b_h));
    out[(size_t)m * DD + dgcol] = hh + e * (1.0f - z) * (n - hh);
  }
}

extern "C" void kernel_launch(void* const* d_in, const int* in_sizes, int n_in,
                              void* d_out, int out_size, void* d_ws, size_t ws_size,
                              hipStream_t stream) {
  const float* x   = (const float*)d_in[0];
  const float* Wih = (const float*)d_in[1];
  const float* Whh = (const float*)d_in[2];
  const float* bih = (const float*)d_in[3];
  const float* bhh = (const float*)d_in[4];
  const float* We  = (const float*)d_in[5];
  const float* be  = (const float*)d_in[6];
  float* out = (float*)d_out;
  const int M = in_sizes[0] / DD;   // 32768

  char* ws = (char*)d_ws;
  unsigned char* Sb8   = (unsigned char*)ws;                         // 32 MB (tiled)
  unsigned char* Wcat8 = (unsigned char*)(ws + (size_t)M * DD);      // 4 MB (tiled)
  float* bias = (float*)(ws + (size_t)M * DD + (size_t)4 * DD * DD);
  float* err  = (float*)(ws + (size_t)M * DD + (size_t)4 * DD * DD + (size_t)4 * DD * 4);

  prep_weights<<<4096, 256, 0, stream>>>(Wih, Whh, bih, bhh, Wcat8, bias);

  const int nwg = (M / 128) * 32;   // 8192
  const float* S = x;
  for (int it = 0; it < 2; ++it) {
    error_cast<<<M, 256, 0, stream>>>(S, We, be, Sb8, err);
    gru_fused_gemm<<<nwg, 256, 0, stream>>>(Sb8, Wcat8, bias, err, S, out, M);
    S = out;
  }
}